// Round 8
// baseline (154.987 us; speedup 1.0000x reference)
//
#include <hip/hip_runtime.h>
#include <math.h>
#include <stdint.h>

#define N_AGENTS 2048
#define R_CAND   128
#define NUM_MODS 6
#define T_STEPS  30
#define B_BATCH  16

// out layout: [0]=cls_loss, [1]=reg_loss, [2..5761]=traj_eval(16,6,30,2), [5762]=num_cls, [5763]=num_reg
// d_ws layout: u64 acc[4] = {cls_fx, reg_fx, ncls, nreg}; u32 ticket at byte 32. Zeroed per launch.

#define FXSCALE 1073741824.0   // 2^30

__global__ __launch_bounds__(128) void agent_kernel(
    const float* __restrict__ roi,      // [N*R,5]
    const float* __restrict__ anchor,   // [N*R,4]
    const float* __restrict__ ctrs,     // [N,2]
    const float* __restrict__ feats,    // [N,20,3]
    const float* __restrict__ gt,       // [N,T,2]
    const int* __restrict__ has,        // [N,T] bool -> int32
    const int* __restrict__ natgs,      // [B]
    float* __restrict__ out,
    unsigned long long* __restrict__ acc)   // [4] fixed-point accumulators + ticket
{
    const int a   = blockIdx.x;
    const int tid = threadIdx.x;

    __shared__ __align__(16) float    s_stage[R_CAND * 5];
    __shared__ float4   s_goal[R_CAND];            // orig order (gx,gy,g2,g3)
    __shared__ __align__(16) float    s_logic[R_CAND];  // orig order
    __shared__ float2   s_pos[R_CAND];             // sorted by logit desc
    __shared__ int      s_sidx[R_CAND];            // sorted pos -> orig idx
    __shared__ float    s_d[R_CAND];               // dist (sorted order)
    __shared__ __align__(16) uint32_t s_col[R_CAND][4]; // suppression columns (bits i<j)
    __shared__ float    s_gtrow[T_STEPS * 2];
    __shared__ int      s_has[T_STEPS];
    __shared__ float    s_coef[NUM_MODS][6];
    __shared__ float    s_traj[NUM_MODS][T_STEPS][2];

    // ---- A1: coalesced staging + column zero-init
    {
        const float* rbase = roi + (size_t)a * R_CAND * 5;
        #pragma unroll
        for (int k = 0; k < 5; ++k) s_stage[tid + k * 128] = rbase[tid + k * 128];
    }
    *reinterpret_cast<uint4*>(&s_col[tid][0]) = make_uint4(0u, 0u, 0u, 0u);
    const float4 anc = *reinterpret_cast<const float4*>(anchor + (size_t)(a * R_CAND + tid) * 4);
    if (tid < T_STEPS * 2) s_gtrow[tid] = gt[(size_t)a * T_STEPS * 2 + tid];
    if (tid >= 64 && tid < 64 + T_STEPS) s_has[tid - 64] = has[(size_t)a * T_STEPS + (tid - 64)];
    __syncthreads();

    // ---- A2: logits + goals (stride-5 LDS read: 5 coprime 32 -> conflict-free)
    float lg, gx, gy;
    {
        const float* rp = &s_stage[tid * 5];
        lg = rp[0];
        gx = anc.x + rp[1];
        gy = anc.y + rp[2];
        s_logic[tid] = lg;
        s_goal[tid]  = make_float4(gx, gy, anc.z + rp[3], anc.w + rp[4]);
    }
    __syncthreads();

    // ---- B: rank = stable argsort(-logic) position; scatter pos/idx/dist
    {
        int rank = 0;
        for (int j = 0; j < R_CAND; j += 4) {
            const float4 v = *reinterpret_cast<const float4*>(&s_logic[j]);
            rank += (v.x > lg) || (v.x == lg && (j + 0) < tid);
            rank += (v.y > lg) || (v.y == lg && (j + 1) < tid);
            rank += (v.z > lg) || (v.z == lg && (j + 2) < tid);
            rank += (v.w > lg) || (v.w == lg && (j + 3) < tid);
        }
        s_pos[rank]  = make_float2(gx, gy);
        s_sidx[rank] = tid;
        s_d[rank]    = fabsf(gx - s_gtrow[(T_STEPS - 1) * 2]) + fabsf(gy - s_gtrow[(T_STEPS - 1) * 2 + 1]);
    }
    __syncthreads();

    // ---- C: balanced all-pairs suppression (round-robin; each lane 63-64 iters)
    //      boxes 0.5x0.5: iou>0.5 <=> wx>0 && wx*wy>1/6, wx=0.5-|dx|
    {
        const int t = tid;
        const float2 pt = s_pos[t];
        const int kmax = (t < 64) ? 64 : 63;   // pair (t,t+64) tested once (by t<64)
        #pragma unroll 4
        for (int k = 1; k <= kmax; ++k) {
            const int p = (t + k) & (R_CAND - 1);
            const float2 pp = s_pos[p];
            const float wx = 0.5f - fabsf(pt.x - pp.x);
            const float wy = 0.5f - fabsf(pt.y - pp.y);
            if (wx > 0.0f && wx * wy > (1.0f / 6.0f)) {   // sparse: ~8 hits/agent total
                const int lo = (p < t) ? p : t;
                const int hi = (p < t) ? t : p;
                atomicOr(&s_col[hi][lo >> 5], 1u << (lo & 31));
            }
        }
    }
    __syncthreads();

    // ---- D (wave 0): ballot-fixpoint NMS -> top-6 -> coefficients
    float my_slog = 0.0f; int my_win = 0;   // valid on lanes 0..5
    if (tid < 64) {
        const uint64_t cl0 = (uint64_t)s_col[tid][0] | ((uint64_t)s_col[tid][1] << 32);       // col tid (<64): word1==0
        const uint64_t ch0 = (uint64_t)s_col[tid + 64][0] | ((uint64_t)s_col[tid + 64][1] << 32);
        const uint64_t ch1 = (uint64_t)s_col[tid + 64][2] | ((uint64_t)s_col[tid + 64][3] << 32);
        uint64_t k0 = ~0ull, k1 = ~0ull;
        for (int it = 0; it < 200; ++it) {                  // fixpoint == greedy NMS
            const int slo = ((cl0 & k0) != 0);
            const int shi = (((ch0 & k0) | (ch1 & k1)) != 0);
            const uint64_t n0 = ~__ballot(slo);
            const uint64_t n1 = ~__ballot(shi);
            if (n0 == k0 && n1 == k1) break;
            k0 = n0; k1 = n1;
        }
        const int kfall = (__popcll(k0) + __popcll(k1)) < NUM_MODS;
        float d_lo = (kfall | (int)((k0 >> tid) & 1)) ? s_d[tid]      : INFINITY;
        float d_hi = (kfall | (int)((k1 >> tid) & 1)) ? s_d[tid + 64] : INFINITY;
        int   i_lo = s_sidx[tid], i_hi = s_sidx[tid + 64];
        for (int m = 0; m < NUM_MODS; ++m) {
            float bd; int bi;
            if (d_lo < d_hi || (d_lo == d_hi && i_lo < i_hi)) { bd = d_lo; bi = i_lo; }
            else                                               { bd = d_hi; bi = i_hi; }
            for (int off = 32; off >= 1; off >>= 1) {
                const float od = __shfl_down(bd, (unsigned)off, 64);
                const int   oi = __shfl_down(bi, (unsigned)off, 64);
                if (od < bd || (od == bd && oi < bi)) { bd = od; bi = oi; }
            }
            bi = __shfl(bi, 0, 64);
            if (tid == m) my_win = bi;
            if (i_lo == bi) d_lo = INFINITY;
            if (i_hi == bi) d_hi = INFINITY;
        }
        if (tid < NUM_MODS) {
            const float ap0 = ctrs[(size_t)a * 2 + 0];
            const float ap1 = ctrs[(size_t)a * 2 + 1];
            const float ap2 = feats[((size_t)a * 20 + 19) * 3 + 0];
            const float ap3 = feats[((size_t)a * 20 + 19) * 3 + 1];
            const float4 g = s_goal[my_win];
            my_slog = s_logic[my_win];
            const float a1c = (2.f * g.x * ap2 + 2.f * ap0 * ap2) / (2.f + ap2 - g.z);
            const float a0c = g.x - ap0 - a1c;
            const float b1c = (2.f * g.y * ap3 + 2.f * ap1 * ap3) / (2.f + ap3 - g.w);
            const float b0c = g.y - ap1 - b1c;
            s_coef[tid][0] = a0c; s_coef[tid][1] = a1c; s_coef[tid][2] = ap0;
            s_coef[tid][3] = b0c; s_coef[tid][4] = b1c; s_coef[tid][5] = ap1;
        }
    }
    __syncthreads();

    // ---- E: trajectories (180 elems, strided)
    for (int p = tid; p < NUM_MODS * T_STEPS; p += 128) {
        const int m = p / T_STEPS, t = p % T_STEPS;
        const float s1 = (float)t / (float)(T_STEPS - 1);
        const float s2 = s1 * s1;
        s_traj[m][t][0] = s_coef[m][0] * s2 + s_coef[m][1] * s1 + s_coef[m][2];
        s_traj[m][t][1] = s_coef[m][3] * s2 + s_coef[m][4] * s1 + s_coef[m][5];
    }
    __syncthreads();

    // ---- F (wave 0): losses + global fixed-point accumulate  ||  G (wave 1): traj_eval gather
    if (tid < 64) {
        float bv = -1e30f; int bt = tid;
        if (tid < T_STEPS) bv = (s_has[tid] ? 1.0f : 0.0f) + (0.1f * (float)tid) / (float)T_STEPS;
        for (int off = 16; off >= 1; off >>= 1) {
            const float ov = __shfl_down(bv, (unsigned)off, 32);
            const int   ot = __shfl_down(bt, (unsigned)off, 32);
            if (ov > bv || (ov == bv && ot < bt)) { bv = ov; bt = ot; }
        }
        const int   lt   = __shfl(bt, 0, 64);
        const float bmax = __shfl(bv, 0, 64);
        const int   mask = bmax > 1.0f;
        const float egx = s_gtrow[lt * 2 + 0], egy = s_gtrow[lt * 2 + 1];
        float md = 1e30f; int mm = tid;
        if (tid < NUM_MODS) {
            const float dx = s_traj[tid][lt][0] - egx;
            const float dy = s_traj[tid][lt][1] - egy;
            md = sqrtf(dx * dx + dy * dy);
        }
        for (int off = 4; off >= 1; off >>= 1) {
            const float ov = __shfl_down(md, (unsigned)off, 8);
            const int   om = __shfl_down(mm, (unsigned)off, 8);
            if (ov < md || (ov == md && om < mm)) { md = ov; mm = om; }
        }
        const int mi = __shfl(mm, 0, 64);
        float cv = 0.0f;
        if (tid < NUM_MODS) {
            const float l = my_slog;
            const float g = (tid == mi) ? 1.0f : 0.0f;
            cv = fmaxf(l, 0.0f) - l * g + log1pf(expf(-fabsf(l)));
        }
        cv += __shfl_xor(cv, 4, 8); cv += __shfl_xor(cv, 2, 8); cv += __shfl_xor(cv, 1, 8);
        float rv = 0.0f;
        if (tid < 2 * T_STEPS) {
            const int t = tid >> 1, c = tid & 1;
            if (mask && s_has[t]) {
                const float diff = s_traj[mi][t][c] - s_gtrow[t * 2 + c];
                const float ad = fabsf(diff);
                rv = (ad < 1.0f) ? 0.5f * diff * diff : (ad - 0.5f);
            }
        }
        for (int off = 32; off >= 1; off >>= 1) rv += __shfl_xor(rv, (unsigned)off, 64);
        const int hv = (tid < T_STEPS) ? s_has[tid] : 0;
        const int nh = __popcll(__ballot(hv != 0));
        if (tid == 0) {
            // deterministic: integer addition is exact & commutative; all terms >= 0
            const unsigned long long c_fx =
                (unsigned long long)__double2ll_rn((double)(mask ? cv : 0.0f) * FXSCALE);
            const unsigned long long r_fx =
                (unsigned long long)__double2ll_rn((double)rv * FXSCALE);
            atomicAdd(&acc[0], c_fx);
            atomicAdd(&acc[1], r_fx);
            atomicAdd(&acc[2], (unsigned long long)(mask ? 1 : 0));
            atomicAdd(&acc[3], (unsigned long long)(mask ? nh : 0));
            __threadfence();
            unsigned int* ticket = (unsigned int*)(acc + 4);
            const unsigned int t = atomicAdd(ticket, 1u);
            if (t == N_AGENTS - 1) {      // last block: all adds are visible (release via fence)
                __threadfence();
                const unsigned long long v0 = __hip_atomic_load(&acc[0], __ATOMIC_RELAXED, __HIP_MEMORY_SCOPE_AGENT);
                const unsigned long long v1 = __hip_atomic_load(&acc[1], __ATOMIC_RELAXED, __HIP_MEMORY_SCOPE_AGENT);
                const unsigned long long v2 = __hip_atomic_load(&acc[2], __ATOMIC_RELAXED, __HIP_MEMORY_SCOPE_AGENT);
                const unsigned long long v3 = __hip_atomic_load(&acc[3], __ATOMIC_RELAXED, __HIP_MEMORY_SCOPE_AGENT);
                out[0]    = (float)((double)v0 / FXSCALE);
                out[1]    = (float)((double)v1 / FXSCALE);
                out[5762] = (float)v2;
                out[5763] = (float)v3;
            }
        }
    } else {
        // gather (temp is NOT cumsum: [0, natgs[0], ..., natgs[14]])
        const float* tp = &s_traj[0][0][0];
        const int p = tid - 64;
        for (int b = 0; b < B_BATCH; ++b) {
            const int target = (b == 0) ? 0 : natgs[b - 1];
            if (target == a) {
                for (int q = p; q < NUM_MODS * T_STEPS * 2; q += 64)
                    out[2 + (size_t)b * NUM_MODS * T_STEPS * 2 + q] = tp[q];
            }
        }
    }
}

extern "C" void kernel_launch(void* const* d_in, const int* in_sizes, int n_in,
                              void* d_out, int out_size, void* d_ws, size_t ws_size,
                              hipStream_t stream) {
    const float*   roi    = (const float*)d_in[0];
    const float*   anchor = (const float*)d_in[1];
    const float*   ctrs   = (const float*)d_in[2];
    const float*   feats  = (const float*)d_in[3];
    const float*   gt     = (const float*)d_in[4];
    const int*     has    = (const int*)d_in[5];
    const int*     natgs  = (const int*)d_in[6];
    float* out = (float*)d_out;
    unsigned long long* acc = (unsigned long long*)d_ws;

    hipMemsetAsync(d_ws, 0, 40, stream);   // acc[0..3] + ticket (graph-capturable)
    agent_kernel<<<N_AGENTS, 128, 0, stream>>>(roi, anchor, ctrs, feats, gt, has, natgs, out, acc);
}

// Round 9
// 28.177 us; speedup vs baseline: 5.5004x; 5.5004x over previous
//
#include <hip/hip_runtime.h>
#include <math.h>
#include <stdint.h>

#define N_AGENTS 2048
#define R_CAND   128
#define NUM_MODS 6
#define T_STEPS  30
#define B_BATCH  16

// out layout: [0]=cls_loss, [1]=reg_loss, [2..5761]=traj_eval(16,6,30,2), [5762]=num_cls, [5763]=num_reg

__global__ __launch_bounds__(256) void agent_kernel(
    const float* __restrict__ roi,      // [N*R,5]
    const float* __restrict__ anchor,   // [N*R,4]
    const float* __restrict__ ctrs,     // [N,2]
    const float* __restrict__ feats,    // [N,20,3]
    const float* __restrict__ gt,       // [N,T,2]
    const int* __restrict__ has,        // [N,T] bool -> int32
    const int* __restrict__ natgs,      // [B]
    float* __restrict__ out,
    float* __restrict__ part)           // [N,4]
{
    const int a   = blockIdx.x;
    const int tid = threadIdx.x;

    __shared__ float4   s_goal[R_CAND];                 // orig order (gx,gy,g2,g3)
    __shared__ __align__(16) float s_logic[R_CAND];     // orig order
    __shared__ float2   s_pos[R_CAND];                  // sorted by logit desc
    __shared__ int      s_sidx[R_CAND];                 // sorted pos -> orig idx
    __shared__ float    s_d[R_CAND];                    // dist (sorted order)
    __shared__ int      s_rank[R_CAND];                 // partial-rank accumulator
    __shared__ __align__(16) uint32_t s_col[R_CAND][4]; // suppression columns (bits i<j)
    __shared__ float    s_gtrow[T_STEPS * 2];
    __shared__ int      s_has[T_STEPS];
    __shared__ float    s_coef[NUM_MODS][6];
    __shared__ float    s_traj[NUM_MODS][T_STEPS][2];

    // ---- A: loads (t<128 own one candidate each) + zero-init
    float lg = 0.0f, gx = 0.0f, gy = 0.0f;
    if (tid < R_CAND) {
        const float* rp  = roi + (size_t)(a * R_CAND + tid) * 5;
        const float4 anc = *reinterpret_cast<const float4*>(anchor + (size_t)(a * R_CAND + tid) * 4);
        lg = rp[0];
        gx = anc.x + rp[1];
        gy = anc.y + rp[2];
        s_logic[tid] = lg;
        s_goal[tid]  = make_float4(gx, gy, anc.z + rp[3], anc.w + rp[4]);
        s_rank[tid]  = 0;
        *reinterpret_cast<uint4*>(&s_col[tid][0]) = make_uint4(0u, 0u, 0u, 0u);
    } else if (tid < 128 + 60) {
        s_gtrow[tid - 128] = gt[(size_t)a * T_STEPS * 2 + (tid - 128)];
    } else if (tid >= 192 && tid < 192 + T_STEPS) {
        s_has[tid - 192] = has[(size_t)a * T_STEPS + (tid - 192)];
    }
    __syncthreads();

    // ---- B1: partial rank (each candidate scanned by 2 threads, 64 logits each)
    {
        const int c = tid & 127, hf = tid >> 7;
        const float lr = s_logic[c];
        const int j0 = hf << 6;
        int pr = 0;
        for (int j = j0; j < j0 + 64; j += 4) {
            const float4 v = *reinterpret_cast<const float4*>(&s_logic[j]);
            pr += (v.x > lr) || (v.x == lr && (j + 0) < c);
            pr += (v.y > lr) || (v.y == lr && (j + 1) < c);
            pr += (v.z > lr) || (v.z == lr && (j + 2) < c);
            pr += (v.w > lr) || (v.w == lr && (j + 3) < c);
        }
        atomicAdd(&s_rank[c], pr);
    }
    __syncthreads();

    // ---- B2: scatter into sorted order (t<128)
    if (tid < R_CAND) {
        const int rank = s_rank[tid];
        s_pos[rank]  = make_float2(gx, gy);
        s_sidx[rank] = tid;
        s_d[rank]    = fabsf(gx - s_gtrow[(T_STEPS - 1) * 2]) + fabsf(gy - s_gtrow[(T_STEPS - 1) * 2 + 1]);
    }
    __syncthreads();

    // ---- C: balanced all-pairs suppression, ~32 iters/lane across 256 threads
    //      boxes 0.5x0.5: iou>0.5 <=> wx>0 && wx*wy>1/6, wx=0.5-|dx|
    {
        const int c = tid & 127, hf = tid >> 7;
        const float2 pt = s_pos[c];
        const int dlo = hf ? 33 : 1;
        const int dhi = hf ? ((c < 64) ? 64 : 63) : 32;   // d=64 pair tested once (c<64)
        for (int d = dlo; d <= dhi; ++d) {
            const int p = (c + d) & (R_CAND - 1);
            const float2 pp = s_pos[p];
            const float wx = 0.5f - fabsf(pt.x - pp.x);
            const float wy = 0.5f - fabsf(pt.y - pp.y);
            if (wx > 0.0f && wx * wy > (1.0f / 6.0f)) {   // sparse: ~8 hits/agent total
                const int lo = (p < c) ? p : c;
                const int hi = (p < c) ? c : p;
                atomicOr(&s_col[hi][lo >> 5], 1u << (lo & 31));
            }
        }
    }
    __syncthreads();

    // ---- D (wave 0): ballot-fixpoint NMS -> top-6 -> coefficients
    float my_slog = 0.0f; int my_win = 0;   // valid on lanes 0..5
    if (tid < 64) {
        const uint64_t cl0 = (uint64_t)s_col[tid][0] | ((uint64_t)s_col[tid][1] << 32);
        const uint64_t ch0 = (uint64_t)s_col[tid + 64][0] | ((uint64_t)s_col[tid + 64][1] << 32);
        const uint64_t ch1 = (uint64_t)s_col[tid + 64][2] | ((uint64_t)s_col[tid + 64][3] << 32);
        uint64_t k0 = ~0ull, k1 = ~0ull;
        for (int it = 0; it < 200; ++it) {                  // fixpoint == greedy NMS
            const int slo = ((cl0 & k0) != 0);
            const int shi = (((ch0 & k0) | (ch1 & k1)) != 0);
            const uint64_t n0 = ~__ballot(slo);
            const uint64_t n1 = ~__ballot(shi);
            if (n0 == k0 && n1 == k1) break;
            k0 = n0; k1 = n1;
        }
        const int kfall = (__popcll(k0) + __popcll(k1)) < NUM_MODS;
        float d_lo = (kfall | (int)((k0 >> tid) & 1)) ? s_d[tid]      : INFINITY;
        float d_hi = (kfall | (int)((k1 >> tid) & 1)) ? s_d[tid + 64] : INFINITY;
        int   i_lo = s_sidx[tid], i_hi = s_sidx[tid + 64];
        for (int m = 0; m < NUM_MODS; ++m) {
            float bd; int bi;
            if (d_lo < d_hi || (d_lo == d_hi && i_lo < i_hi)) { bd = d_lo; bi = i_lo; }
            else                                               { bd = d_hi; bi = i_hi; }
            for (int off = 32; off >= 1; off >>= 1) {
                const float od = __shfl_down(bd, (unsigned)off, 64);
                const int   oi = __shfl_down(bi, (unsigned)off, 64);
                if (od < bd || (od == bd && oi < bi)) { bd = od; bi = oi; }
            }
            bi = __shfl(bi, 0, 64);
            if (tid == m) my_win = bi;
            if (i_lo == bi) d_lo = INFINITY;
            if (i_hi == bi) d_hi = INFINITY;
        }
        if (tid < NUM_MODS) {
            const float ap0 = ctrs[(size_t)a * 2 + 0];
            const float ap1 = ctrs[(size_t)a * 2 + 1];
            const float ap2 = feats[((size_t)a * 20 + 19) * 3 + 0];
            const float ap3 = feats[((size_t)a * 20 + 19) * 3 + 1];
            const float4 g = s_goal[my_win];
            my_slog = s_logic[my_win];
            const float a1c = (2.f * g.x * ap2 + 2.f * ap0 * ap2) / (2.f + ap2 - g.z);
            const float a0c = g.x - ap0 - a1c;
            const float b1c = (2.f * g.y * ap3 + 2.f * ap1 * ap3) / (2.f + ap3 - g.w);
            const float b0c = g.y - ap1 - b1c;
            s_coef[tid][0] = a0c; s_coef[tid][1] = a1c; s_coef[tid][2] = ap0;
            s_coef[tid][3] = b0c; s_coef[tid][4] = b1c; s_coef[tid][5] = ap1;
        }
    }
    __syncthreads();

    // ---- E: trajectories (180 elems over 256 threads)
    if (tid < NUM_MODS * T_STEPS) {
        const int m = tid / T_STEPS, t = tid % T_STEPS;
        const float s1 = (float)t / (float)(T_STEPS - 1);
        const float s2 = s1 * s1;
        s_traj[m][t][0] = s_coef[m][0] * s2 + s_coef[m][1] * s1 + s_coef[m][2];
        s_traj[m][t][1] = s_coef[m][3] * s2 + s_coef[m][4] * s1 + s_coef[m][5];
    }
    __syncthreads();

    // ---- F (wave 0): losses  ||  G (wave 1): traj_eval gather; waves 2-3 exit
    if (tid < 64) {
        float bv = -1e30f; int bt = tid;
        if (tid < T_STEPS) bv = (s_has[tid] ? 1.0f : 0.0f) + (0.1f * (float)tid) / (float)T_STEPS;
        for (int off = 16; off >= 1; off >>= 1) {
            const float ov = __shfl_down(bv, (unsigned)off, 32);
            const int   ot = __shfl_down(bt, (unsigned)off, 32);
            if (ov > bv || (ov == bv && ot < bt)) { bv = ov; bt = ot; }
        }
        const int   lt   = __shfl(bt, 0, 64);
        const float bmax = __shfl(bv, 0, 64);
        const int   mask = bmax > 1.0f;
        const float egx = s_gtrow[lt * 2 + 0], egy = s_gtrow[lt * 2 + 1];
        float md = 1e30f; int mm = tid;
        if (tid < NUM_MODS) {
            const float dx = s_traj[tid][lt][0] - egx;
            const float dy = s_traj[tid][lt][1] - egy;
            md = sqrtf(dx * dx + dy * dy);
        }
        for (int off = 4; off >= 1; off >>= 1) {
            const float ov = __shfl_down(md, (unsigned)off, 8);
            const int   om = __shfl_down(mm, (unsigned)off, 8);
            if (ov < md || (ov == md && om < mm)) { md = ov; mm = om; }
        }
        const int mi = __shfl(mm, 0, 64);
        float cv = 0.0f;
        if (tid < NUM_MODS) {
            const float l = my_slog;
            const float g = (tid == mi) ? 1.0f : 0.0f;
            cv = fmaxf(l, 0.0f) - l * g + log1pf(expf(-fabsf(l)));
        }
        cv += __shfl_xor(cv, 4, 8); cv += __shfl_xor(cv, 2, 8); cv += __shfl_xor(cv, 1, 8);
        float rv = 0.0f;
        if (tid < 2 * T_STEPS) {
            const int t = tid >> 1, c = tid & 1;
            if (mask && s_has[t]) {
                const float diff = s_traj[mi][t][c] - s_gtrow[t * 2 + c];
                const float ad = fabsf(diff);
                rv = (ad < 1.0f) ? 0.5f * diff * diff : (ad - 0.5f);
            }
        }
        for (int off = 32; off >= 1; off >>= 1) rv += __shfl_xor(rv, (unsigned)off, 64);
        const int hv = (tid < T_STEPS) ? s_has[tid] : 0;
        const int nh = __popcll(__ballot(hv != 0));
        if (tid == 0) {
            *reinterpret_cast<float4*>(&part[(size_t)a * 4]) =
                make_float4(mask ? cv : 0.0f, rv, mask ? 1.0f : 0.0f, mask ? (float)nh : 0.0f);
        }
    } else if (tid < 128) {
        // gather (temp is NOT cumsum: [0, natgs[0], ..., natgs[14]])
        const float* tp = &s_traj[0][0][0];
        const int p = tid - 64;
        for (int b = 0; b < B_BATCH; ++b) {
            const int target = (b == 0) ? 0 : natgs[b - 1];
            if (target == a) {
                for (int q = p; q < NUM_MODS * T_STEPS * 2; q += 64)
                    out[2 + (size_t)b * NUM_MODS * T_STEPS * 2 + q] = tp[q];
            }
        }
    }
}

__global__ __launch_bounds__(256) void reduce_kernel(
    const float* __restrict__ part, float* __restrict__ out)
{
    __shared__ double s0[256], s1[256], s2[256], s3[256];
    const int tid = threadIdx.x;
    double c = 0, r = 0, n = 0, w = 0;
    for (int a = tid; a < N_AGENTS; a += 256) {
        c += (double)part[(size_t)a * 4 + 0];
        r += (double)part[(size_t)a * 4 + 1];
        n += (double)part[(size_t)a * 4 + 2];
        w += (double)part[(size_t)a * 4 + 3];
    }
    s0[tid] = c; s1[tid] = r; s2[tid] = n; s3[tid] = w;
    __syncthreads();
    for (int off = 128; off >= 1; off >>= 1) {
        if (tid < off) {
            s0[tid] += s0[tid + off]; s1[tid] += s1[tid + off];
            s2[tid] += s2[tid + off]; s3[tid] += s3[tid + off];
        }
        __syncthreads();
    }
    if (tid == 0) {
        out[0]    = (float)s0[0];
        out[1]    = (float)s1[0];
        out[5762] = (float)s2[0];
        out[5763] = (float)s3[0];
    }
}

extern "C" void kernel_launch(void* const* d_in, const int* in_sizes, int n_in,
                              void* d_out, int out_size, void* d_ws, size_t ws_size,
                              hipStream_t stream) {
    const float*   roi    = (const float*)d_in[0];
    const float*   anchor = (const float*)d_in[1];
    const float*   ctrs   = (const float*)d_in[2];
    const float*   feats  = (const float*)d_in[3];
    const float*   gt     = (const float*)d_in[4];
    const int*     has    = (const int*)d_in[5];
    const int*     natgs  = (const int*)d_in[6];
    float* out  = (float*)d_out;
    float* part = (float*)d_ws;   // 2048*4 floats = 32 KB

    agent_kernel<<<N_AGENTS, 256, 0, stream>>>(roi, anchor, ctrs, feats, gt, has, natgs, out, part);
    reduce_kernel<<<1, 256, 0, stream>>>(part, out);
}

// Round 10
// 22.763 us; speedup vs baseline: 6.8087x; 1.2379x over previous
//
#include <hip/hip_runtime.h>
#include <math.h>
#include <stdint.h>

#define N_AGENTS 2048
#define R_CAND   128
#define NUM_MODS 6
#define T_STEPS  30
#define B_BATCH  16

// out layout: [0]=cls_loss, [1]=reg_loss, [2..5761]=traj_eval(16,6,30,2), [5762]=num_cls, [5763]=num_reg

__global__ __launch_bounds__(256) void agent_kernel(
    const float* __restrict__ roi,      // [N*R,5]
    const float* __restrict__ anchor,   // [N*R,4]
    const float* __restrict__ ctrs,     // [N,2]
    const float* __restrict__ feats,    // [N,20,3]
    const float* __restrict__ gt,       // [N,T,2]
    const int* __restrict__ has,        // [N,T] bool -> int32
    const int* __restrict__ natgs,      // [B]
    float* __restrict__ out,
    float* __restrict__ part)           // [N,4]
{
    const int a   = blockIdx.x;
    const int tid = threadIdx.x;

    // Everything in ORIGINAL candidate order — no sort. NMS priority handled
    // at pair-test time via (logit, idx) comparison; ballot-fixpoint converges
    // to greedy NMS independent of lane arrangement (unique fixpoint).
    __shared__ float4   s_goal[R_CAND];                 // (gx,gy,g2,g3)
    __shared__ float    s_logic[R_CAND];
    __shared__ float2   s_pos[R_CAND];                  // (gx,gy) for pair loop
    __shared__ float    s_d[R_CAND];                    // dist to gt endpoint
    __shared__ __align__(16) uint32_t s_col[R_CAND][4]; // full 128-bit suppressor columns
    __shared__ float    s_gtrow[T_STEPS * 2];
    __shared__ int      s_has[T_STEPS];
    __shared__ float    s_coef[NUM_MODS][6];
    __shared__ float    s_traj[NUM_MODS][T_STEPS][2];

    // ---- A: loads (t<128 own one candidate each) + zero-init
    float gx = 0.0f, gy = 0.0f;
    if (tid < R_CAND) {
        const float* rp  = roi + (size_t)(a * R_CAND + tid) * 5;
        const float4 anc = *reinterpret_cast<const float4*>(anchor + (size_t)(a * R_CAND + tid) * 4);
        const float lg = rp[0];
        gx = anc.x + rp[1];
        gy = anc.y + rp[2];
        s_logic[tid] = lg;
        s_goal[tid]  = make_float4(gx, gy, anc.z + rp[3], anc.w + rp[4]);
        s_pos[tid]   = make_float2(gx, gy);
        *reinterpret_cast<uint4*>(&s_col[tid][0]) = make_uint4(0u, 0u, 0u, 0u);
    } else if (tid < 128 + 60) {
        s_gtrow[tid - 128] = gt[(size_t)a * T_STEPS * 2 + (tid - 128)];
    } else if (tid >= 192 && tid < 192 + T_STEPS) {
        s_has[tid - 192] = has[(size_t)a * T_STEPS + (tid - 192)];
    }
    __syncthreads();

    // ---- C: balanced all-pairs suppression, ~32 iters/lane across 256 threads
    //      boxes 0.5x0.5: iou>0.5 <=> wx>0 && wx*wy>1/6, wx=0.5-|dx|
    //      On (sparse) hit: higher (logit, -idx) priority suppresses the other.
    {
        const int c = tid & 127, hf = tid >> 7;
        if (hf == 0) s_d[c] = fabsf(gx - s_gtrow[(T_STEPS - 1) * 2]) +
                              fabsf(gy - s_gtrow[(T_STEPS - 1) * 2 + 1]);
        const float2 pt = s_pos[c];
        const int dlo = hf ? 33 : 1;
        const int dhi = hf ? ((c < 64) ? 64 : 63) : 32;   // d=64 pair tested once (c<64)
        for (int d = dlo; d <= dhi; ++d) {
            const int p = (c + d) & (R_CAND - 1);
            const float2 pp = s_pos[p];
            const float wx = 0.5f - fabsf(pt.x - pp.x);
            const float wy = 0.5f - fabsf(pt.y - pp.y);
            if (wx > 0.0f && wx * wy > (1.0f / 6.0f)) {   // ~8 hits per agent total
                const float lgc = s_logic[c], lgp = s_logic[p];
                const int p_wins = (lgp > lgc) || (lgp == lgc && p < c);
                const int sup  = p_wins ? c : p;          // suppressed candidate
                const int by   = p_wins ? p : c;          // suppressor
                atomicOr(&s_col[sup][by >> 5], 1u << (by & 31));
            }
        }
    }
    __syncthreads();

    // ---- D (wave 0): ballot-fixpoint NMS -> top-6 -> coefficients
    float my_slog = 0.0f; int my_win = 0;   // valid on lanes 0..5
    if (tid < 64) {
        const uint64_t cA0 = (uint64_t)s_col[tid][0]      | ((uint64_t)s_col[tid][1]      << 32);
        const uint64_t cA1 = (uint64_t)s_col[tid][2]      | ((uint64_t)s_col[tid][3]      << 32);
        const uint64_t cB0 = (uint64_t)s_col[tid + 64][0] | ((uint64_t)s_col[tid + 64][1] << 32);
        const uint64_t cB1 = (uint64_t)s_col[tid + 64][2] | ((uint64_t)s_col[tid + 64][3] << 32);
        uint64_t k0 = ~0ull, k1 = ~0ull;
        for (int it = 0; it < 200; ++it) {                  // fixpoint == greedy NMS
            const int slo = (((cA0 & k0) | (cA1 & k1)) != 0);
            const int shi = (((cB0 & k0) | (cB1 & k1)) != 0);
            const uint64_t n0 = ~__ballot(slo);
            const uint64_t n1 = ~__ballot(shi);
            if (n0 == k0 && n1 == k1) break;
            k0 = n0; k1 = n1;
        }
        const int kfall = (__popcll(k0) + __popcll(k1)) < NUM_MODS;
        float d_lo = (kfall | (int)((k0 >> tid) & 1)) ? s_d[tid]      : INFINITY;
        float d_hi = (kfall | (int)((k1 >> tid) & 1)) ? s_d[tid + 64] : INFINITY;
        int   i_lo = tid, i_hi = tid + 64;                  // original indices
        for (int m = 0; m < NUM_MODS; ++m) {
            float bd; int bi;
            if (d_lo < d_hi || (d_lo == d_hi && i_lo < i_hi)) { bd = d_lo; bi = i_lo; }
            else                                               { bd = d_hi; bi = i_hi; }
            for (int off = 32; off >= 1; off >>= 1) {
                const float od = __shfl_down(bd, (unsigned)off, 64);
                const int   oi = __shfl_down(bi, (unsigned)off, 64);
                if (od < bd || (od == bd && oi < bi)) { bd = od; bi = oi; }
            }
            bi = __shfl(bi, 0, 64);
            if (tid == m) my_win = bi;
            if (i_lo == bi) d_lo = INFINITY;
            if (i_hi == bi) d_hi = INFINITY;
        }
        if (tid < NUM_MODS) {
            const float ap0 = ctrs[(size_t)a * 2 + 0];
            const float ap1 = ctrs[(size_t)a * 2 + 1];
            const float ap2 = feats[((size_t)a * 20 + 19) * 3 + 0];
            const float ap3 = feats[((size_t)a * 20 + 19) * 3 + 1];
            const float4 g = s_goal[my_win];
            my_slog = s_logic[my_win];
            const float a1c = (2.f * g.x * ap2 + 2.f * ap0 * ap2) / (2.f + ap2 - g.z);
            const float a0c = g.x - ap0 - a1c;
            const float b1c = (2.f * g.y * ap3 + 2.f * ap1 * ap3) / (2.f + ap3 - g.w);
            const float b0c = g.y - ap1 - b1c;
            s_coef[tid][0] = a0c; s_coef[tid][1] = a1c; s_coef[tid][2] = ap0;
            s_coef[tid][3] = b0c; s_coef[tid][4] = b1c; s_coef[tid][5] = ap1;
        }
    }
    __syncthreads();

    // ---- E: trajectories (180 elems over 256 threads)
    if (tid < NUM_MODS * T_STEPS) {
        const int m = tid / T_STEPS, t = tid % T_STEPS;
        const float s1 = (float)t / (float)(T_STEPS - 1);
        const float s2 = s1 * s1;
        s_traj[m][t][0] = s_coef[m][0] * s2 + s_coef[m][1] * s1 + s_coef[m][2];
        s_traj[m][t][1] = s_coef[m][3] * s2 + s_coef[m][4] * s1 + s_coef[m][5];
    }
    __syncthreads();

    // ---- F (wave 0): losses  ||  G (wave 1): traj_eval gather; waves 2-3 done
    if (tid < 64) {
        float bv = -1e30f; int bt = tid;
        if (tid < T_STEPS) bv = (s_has[tid] ? 1.0f : 0.0f) + (0.1f * (float)tid) / (float)T_STEPS;
        for (int off = 16; off >= 1; off >>= 1) {
            const float ov = __shfl_down(bv, (unsigned)off, 32);
            const int   ot = __shfl_down(bt, (unsigned)off, 32);
            if (ov > bv || (ov == bv && ot < bt)) { bv = ov; bt = ot; }
        }
        const int   lt   = __shfl(bt, 0, 64);
        const float bmax = __shfl(bv, 0, 64);
        const int   mask = bmax > 1.0f;
        const float egx = s_gtrow[lt * 2 + 0], egy = s_gtrow[lt * 2 + 1];
        float md = 1e30f; int mm = tid;
        if (tid < NUM_MODS) {
            const float dx = s_traj[tid][lt][0] - egx;
            const float dy = s_traj[tid][lt][1] - egy;
            md = sqrtf(dx * dx + dy * dy);
        }
        for (int off = 4; off >= 1; off >>= 1) {
            const float ov = __shfl_down(md, (unsigned)off, 8);
            const int   om = __shfl_down(mm, (unsigned)off, 8);
            if (ov < md || (ov == md && om < mm)) { md = ov; mm = om; }
        }
        const int mi = __shfl(mm, 0, 64);
        float cv = 0.0f;
        if (tid < NUM_MODS) {
            const float l = my_slog;
            const float g = (tid == mi) ? 1.0f : 0.0f;
            cv = fmaxf(l, 0.0f) - l * g + log1pf(expf(-fabsf(l)));
        }
        cv += __shfl_xor(cv, 4, 8); cv += __shfl_xor(cv, 2, 8); cv += __shfl_xor(cv, 1, 8);
        float rv = 0.0f;
        if (tid < 2 * T_STEPS) {
            const int t = tid >> 1, c = tid & 1;
            if (mask && s_has[t]) {
                const float diff = s_traj[mi][t][c] - s_gtrow[t * 2 + c];
                const float ad = fabsf(diff);
                rv = (ad < 1.0f) ? 0.5f * diff * diff : (ad - 0.5f);
            }
        }
        for (int off = 32; off >= 1; off >>= 1) rv += __shfl_xor(rv, (unsigned)off, 64);
        const int hv = (tid < T_STEPS) ? s_has[tid] : 0;
        const int nh = __popcll(__ballot(hv != 0));
        if (tid == 0) {
            *reinterpret_cast<float4*>(&part[(size_t)a * 4]) =
                make_float4(mask ? cv : 0.0f, rv, mask ? 1.0f : 0.0f, mask ? (float)nh : 0.0f);
        }
    } else if (tid < 128) {
        // gather (temp is NOT cumsum: [0, natgs[0], ..., natgs[14]])
        const float* tp = &s_traj[0][0][0];
        const int p = tid - 64;
        for (int b = 0; b < B_BATCH; ++b) {
            const int target = (b == 0) ? 0 : natgs[b - 1];
            if (target == a) {
                for (int q = p; q < NUM_MODS * T_STEPS * 2; q += 64)
                    out[2 + (size_t)b * NUM_MODS * T_STEPS * 2 + q] = tp[q];
            }
        }
    }
}

__global__ __launch_bounds__(256) void reduce_kernel(
    const float* __restrict__ part, float* __restrict__ out)
{
    __shared__ double s0[256], s1[256], s2[256], s3[256];
    const int tid = threadIdx.x;
    double c = 0, r = 0, n = 0, w = 0;
    for (int a = tid; a < N_AGENTS; a += 256) {
        c += (double)part[(size_t)a * 4 + 0];
        r += (double)part[(size_t)a * 4 + 1];
        n += (double)part[(size_t)a * 4 + 2];
        w += (double)part[(size_t)a * 4 + 3];
    }
    s0[tid] = c; s1[tid] = r; s2[tid] = n; s3[tid] = w;
    __syncthreads();
    for (int off = 128; off >= 1; off >>= 1) {
        if (tid < off) {
            s0[tid] += s0[tid + off]; s1[tid] += s1[tid + off];
            s2[tid] += s2[tid + off]; s3[tid] += s3[tid + off];
        }
        __syncthreads();
    }
    if (tid == 0) {
        out[0]    = (float)s0[0];
        out[1]    = (float)s1[0];
        out[5762] = (float)s2[0];
        out[5763] = (float)s3[0];
    }
}

extern "C" void kernel_launch(void* const* d_in, const int* in_sizes, int n_in,
                              void* d_out, int out_size, void* d_ws, size_t ws_size,
                              hipStream_t stream) {
    const float*   roi    = (const float*)d_in[0];
    const float*   anchor = (const float*)d_in[1];
    const float*   ctrs   = (const float*)d_in[2];
    const float*   feats  = (const float*)d_in[3];
    const float*   gt     = (const float*)d_in[4];
    const int*     has    = (const int*)d_in[5];
    const int*     natgs  = (const int*)d_in[6];
    float* out  = (float*)d_out;
    float* part = (float*)d_ws;   // 2048*4 floats = 32 KB

    agent_kernel<<<N_AGENTS, 256, 0, stream>>>(roi, anchor, ctrs, feats, gt, has, natgs, out, part);
    reduce_kernel<<<1, 256, 0, stream>>>(part, out);
}